// Round 12
// baseline (179.145 us; speedup 1.0000x reference)
//
#include <hip/hip_runtime.h>
#include <hip/hip_bf16.h>

// Lovasz loss via bucketed counting-sort reformulation.
// R2: LDS-private histograms replaced global atomics (1917 -> 219 us).
// R3: parallel merge kernel, float scan (219 -> 154).
// R4: cooperative fusion NEUTRAL (grid.sync ~30 us each on 8 XCDs).
// R5: two plain dispatches (156.6); harness reset (256 MiB ws fill 41 us +
//     input restores) is FIXED cost inside the timed window (~80 us).
// R6-R11: NB 1024, BN 16, 1024-thr blocks, uint4 merge, shfl scan (127.5).
// R12: single dispatch. Producer-consumer fusion: the block finishing the
//     16th slice of sample n scans n's two segments (release/acquire via
//     device-scope atomicAdd + __threadfence, rocPRIM-lookback style).
//     Counters need no init: ws poisoned to 0xAA -> accept old==K or
//     old==0xAAAAAAAA+K (disjoint; exactly one winner either way).

#define NB    1024      // buckets; worst-case final err 7.6e-5 < 1.67e-4
#define NSEG  64        // C*N
#define PLOG  18        // P = 262144
#define NN    32
#define PTOT  (1 << PLOG)
#define BN    16            // slices per sample
#define HT    1024          // block size (16 waves)
#define B0_LO (NB / 4)      // mask0: x>0.25  <=> bucket >= NB/4
#define B1_HI (3 * NB / 4)  // mask1: x>0.25  <=> bucket <  3*NB/4
#define POIS  0xAAAAAAAAu

// partial layout: [n][slice][c][b] u32 packed (n1<<16)|n0, slice in [0,BN).
// addr(n,s,c,b) = ((n*BN+s)*2 + c)*NB + b.  Total 4 MiB.

__global__ __launch_bounds__(HT, 8) void fused_k(
    const float* __restrict__ x, const int* __restrict__ tgt,
    unsigned* __restrict__ partial, unsigned* __restrict__ sample_done,
    unsigned* __restrict__ done, float* __restrict__ segval,
    unsigned* __restrict__ segvalid, const float* __restrict__ cw,
    const float* __restrict__ tw, float* __restrict__ out)
{
    __shared__ unsigned hl[2 * NB];   // 8 KB: hist, then reused as mh0/mh1
    __shared__ unsigned wA[16], wS[16], wC[16];
    __shared__ int      wM[16];
    __shared__ float    wF[16];
    __shared__ unsigned sflag, fflag;

    const int g   = blockIdx.x;       // 512 blocks
    const int n   = g >> 4;
    const int sl  = g & (BN - 1);
    const int tid = threadIdx.x;
    const int lane = tid & 63;
    const int wid  = tid >> 6;

    // ---------------- hist phase (R11 body) ----------------
    for (int i = tid; i < 2 * NB; i += HT) hl[i] = 0;
    __syncthreads();

    const int pairs = PTOT / BN;      // 16384
    const int base  = sl * pairs;
    const float* x0 = x + (((long long)n * 2) << PLOG);
    const float* x1 = x0 + PTOT;
    const int*   tg = tgt + ((long long)n << PLOG);

#pragma unroll
    for (int it = 0; it < 4; ++it) {
        const int p = base + it * HT * 4 + tid * 4;
        float4 a  = *(const float4*)(x0 + p);
        float4 b  = *(const float4*)(x1 + p);
        int4   t4 = *(const int4*)(tg + p);
        float xa[4] = {a.x, a.y, a.z, a.w};
        float xb[4] = {b.x, b.y, b.z, b.w};
        int   tt[4] = {t4.x, t4.y, t4.z, t4.w};
#pragma unroll
        for (int k = 0; k < 4; ++k) {
            const bool m0 = (tt[k] == 0);
            const bool m1 = (tt[k] == 1);
            float d0 = m0 ? 1.0f - xa[k] : xa[k];
            float d1 = m1 ? 1.0f - xb[k] : xb[k];
            int b0 = min((int)(d0 * (float)NB), NB - 1);
            int b1 = min((int)(d1 * (float)NB), NB - 1);
            atomicAdd(&hl[b0],      m0 ? 0x10000u : 1u);
            atomicAdd(&hl[NB + b1], m1 ? 0x10000u : 1u);
        }
    }
    __syncthreads();
    unsigned* outp = partial + (size_t)g * (2 * NB);
    for (int i = tid; i < 2 * NB; i += HT) outp[i] = hl[i];
    __syncthreads();                         // all flush stores issued+waited

    // ---------------- release + elect scanner ----------------
    if (tid == 0) {
        __threadfence();                     // publish partial stores
        unsigned old = atomicAdd(&sample_done[n], 1u);
        sflag = (old == BN - 1 || old == POIS + BN - 1) ? 1u : 0u;
    }
    __syncthreads();
    if (!sflag) return;

    // ---------------- scanner: merge + scan both segments ----------------
    __threadfence();                         // acquire partials of all slices
    unsigned* mh0 = hl;                      // reuse hist LDS
    unsigned* mh1 = hl + NB;

    for (int c = 0; c < 2; ++c) {
        __syncthreads();
        mh0[tid] = 0; mh1[tid] = 0;
        __syncthreads();

        {   // merge: (q,t)=(tid>>8, tid&255); 4 slices x uint4 per thread
            const int q = tid >> 8;
            const int t = tid & 255;
            const unsigned* basep = partial +
                (((size_t)(n * BN + q * 4) * 2) + c) * NB + 4 * t;
            unsigned n0v[4] = {0, 0, 0, 0}, n1v[4] = {0, 0, 0, 0};
#pragma unroll
            for (int s = 0; s < 4; ++s) {
                uint4 v = *(const uint4*)(basep + (size_t)s * (2 * NB));
                n0v[0] += v.x & 0xFFFFu; n1v[0] += v.x >> 16;
                n0v[1] += v.y & 0xFFFFu; n1v[1] += v.y >> 16;
                n0v[2] += v.z & 0xFFFFu; n1v[2] += v.z >> 16;
                n0v[3] += v.w & 0xFFFFu; n1v[3] += v.w >> 16;
            }
#pragma unroll
            for (int j = 0; j < 4; ++j) {
                atomicAdd(&mh0[4 * t + j], n0v[j]);
                atomicAdd(&mh1[4 * t + j], n1v[j]);
            }
        }
        __syncthreads();

        // scan: thread tid owns bucket b = NB-1-tid
        const int b = NB - 1 - tid;
        const unsigned n0 = mh0[b], n1 = mh1[b];
        const unsigned tot = n0 + n1;

        unsigned iA = tot, iS = n1;
#pragma unroll
        for (int off = 1; off < 64; off <<= 1) {
            unsigned tA = __shfl_up(iA, off, 64);
            unsigned tS = __shfl_up(iS, off, 64);
            if (lane >= off) { iA += tA; iS += tS; }
        }
        if (lane == 63) { wA[wid] = iA; wS[wid] = iS; }

        unsigned cgt = ((b >= B0_LO) ? n0 : 0u) + ((b < B1_HI) ? n1 : 0u);
        int mb = (n0 | n1) ? b : -1;
#pragma unroll
        for (int off = 1; off < 64; off <<= 1) {
            cgt += __shfl_xor(cgt, off, 64);
            mb = max(mb, __shfl_xor(mb, off, 64));
        }
        if (lane == 0) { wC[wid] = cgt; wM[wid] = mb; }
        __syncthreads();

        if (tid < 16) {
            unsigned a2 = wA[tid], s2 = wS[tid];
#pragma unroll
            for (int off = 1; off < 16; off <<= 1) {
                unsigned tA = __shfl_up(a2, off, 64);
                unsigned tS = __shfl_up(s2, off, 64);
                if (tid >= off) { a2 += tA; s2 += tS; }
            }
            wA[tid] = a2; wS[tid] = s2;
        }
        __syncthreads();

        const unsigned gts   = wS[15];
        const unsigned exclA = iA - tot + (wid ? wA[wid - 1] : 0u);
        const unsigned exclS = iS - n1  + (wid ? wS[wid - 1] : 0u);

        float per_local = 0.0f;
        if (gts > 0 && (n0 | n1)) {
            float d_rep = ((float)b + 0.5f) * (1.0f / (float)NB);
            float U = (float)(gts + exclA - exclS);
            if (n1) per_local += (float)n1 * d_rep / U;
            unsigned s = exclS + n1;
            unsigned inter = gts - s;
            if (n0 && inter)
                per_local += d_rep * (float)inter * (float)n0 /
                             (U * (U + (float)n0));
        }
#pragma unroll
        for (int off = 1; off < 64; off <<= 1)
            per_local += __shfl_xor(per_local, off, 64);
        if (lane == 0) wF[wid] = per_local;
        __syncthreads();

        if (tid == 0) {
            float per = 0.0f;
            unsigned cntgt = 0;
            int max_b = -1;
            for (int i = 0; i < 16; ++i) {
                per += wF[i]; cntgt += wC[i]; max_b = max(max_b, wM[i]);
            }
            if (gts == 0)
                per = (max_b >= 0)
                    ? ((float)max_b + 0.5f) * (1.0f / (float)NB) : 0.0f;
            const bool empty = (gts == 0) && (cntgt == 0);
            const float cwv = cw[c], twv = tw[n];
            const bool valid = (cwv != 0.0f) && !empty;
            const int seg = (c << 5) | n;
            segval[seg]   = valid ? per * twv * cwv : 0.0f;
            segvalid[seg] = valid ? 1u : 0u;
        }
    }

    // ---------------- release + elect finalizer ----------------
    if (tid == 0) {
        __threadfence();                     // publish segval/segvalid
        unsigned old2 = atomicAdd(done, 1u);
        fflag = (old2 == NN - 1 || old2 == POIS + NN - 1) ? 1u : 0u;
    }
    __syncthreads();
    if (fflag && tid < 64) {
        __threadfence();                     // acquire segval/segvalid
        float    lv = segval[tid];
        unsigned vv = segvalid[tid];
        for (int off = 32; off > 0; off >>= 1) {
            lv += __shfl_down(lv, off);
            vv += __shfl_down(vv, off);
        }
        if (tid == 0) out[0] = lv / (float)NN / (float)vv;
    }
}

extern "C" void kernel_launch(void* const* d_in, const int* in_sizes, int n_in,
                              void* d_out, int out_size, void* d_ws, size_t ws_size,
                              hipStream_t stream)
{
    const float* x   = (const float*)d_in[0];   // [32,2,512,512] f32
    const int*   tgt = (const int*)d_in[1];     // [32,512,512] int
    const float* cw  = (const float*)d_in[2];   // [2]
    const float* tw  = (const float*)d_in[3];   // [32]
    float* out = (float*)d_out;

    // ws layout (all counters live on poisoned 0xAA bytes -- by design):
    // [0,128)    sample_done[32] u32
    // [128,132)  done u32
    // [256,512)  segval f32[64]
    // [512,768)  segvalid u32[64]
    // [1024, 1024 + 4 MiB) partial
    unsigned* sample_done = (unsigned*)d_ws;
    unsigned* done        = (unsigned*)((char*)d_ws + 128);
    float*    segval      = (float*)((char*)d_ws + 256);
    unsigned* segvalid    = (unsigned*)((char*)d_ws + 512);
    unsigned* partial     = (unsigned*)((char*)d_ws + 1024);

    fused_k<<<NN * BN, HT, 0, stream>>>(x, tgt, partial, sample_done, done,
                                        segval, segvalid, cw, tw, out);
}

// Round 13
// 127.014 us; speedup vs baseline: 1.4104x; 1.4104x over previous
//
#include <hip/hip_runtime.h>
#include <hip/hip_bf16.h>

// Lovasz loss via bucketed counting-sort reformulation.
// R2: LDS-private histograms replaced global atomics (1917 -> 219 us).
// R3: parallel merge kernel, float scan (219 -> 154).
// R4: cooperative fusion NEUTRAL (grid.sync ~30 us each on 8 XCDs).
// R5: two plain dispatches (156.6); harness reset (256 MiB ws fill 41 us +
//     input restores ~30 us) is FIXED cost inside the timed window (~80 us).
// R6: NB 1024, reg-resident shfl scan (134.5).
// R7: ST 256 + uint4: REGRESSED (145.6) -- waves buy MLP at ~500cy LLC.
// R8: uint4 merge at ST=1024 (132.5).
// R9: hist load pipelining NEUTRAL (131.3).
// R10: BN 16, 1024-thread hist blocks, partial 4 MiB (128.7).
// R11: launch_bounds fix attempt, NEUTRAL (127.5). BEST.
// R12: single-dispatch producer-consumer fusion: REGRESSED (179; kernel
//      113-126 us at 3% VALUBusy). Device-scope __threadfence per block =
//      L2 writeback/invalidate storms that poison the XCD caches the hist
//      streaming depends on. Lesson: kernel boundary IS the cheap sync.
// R13: exact revert to R11.

#define NB    1024      // buckets; worst-case final err 7.6e-5 < 1.67e-4
#define NSEG  64        // C*N
#define PLOG  18        // P = 262144
#define NN    32
#define PTOT  (1 << PLOG)
#define BN    16            // slices per sample (compile-time)
#define HT    1024          // hist block size (16 waves)
#define B0_LO (NB / 4)      // mask0: x>0.25  <=> bucket >= NB/4
#define B1_HI (3 * NB / 4)  // mask1: x>0.25  <=> bucket <  3*NB/4
#define ST    1024          // mergescan block size == NB (1 bucket/thread scan)

// partial layout: [n][slice][c][b] u32 packed (n1<<16)|n0, slice in [0,BN).
// addr(n,s,c,b) = ((n*BN+s)*2 + c)*NB + b.  Total 4 MiB.
// per-slice elements = PTOT/BN = 16384 <= 65535 -> u16 fields safe.

// ---------------- Kernel 1: LDS histogram (+ accumulator init) --------------
__global__ __launch_bounds__(HT, 8) void hist_k(
    const float* __restrict__ x, const int* __restrict__ tgt,
    unsigned* __restrict__ partial, float* __restrict__ loss_sum,
    unsigned* __restrict__ valid_cnt, unsigned* __restrict__ done)
{
    __shared__ unsigned hl[2 * NB];   // 8 KB
    const int g   = blockIdx.x;       // 512 blocks
    const int n   = g >> 4;           // g / BN
    const int sl  = g & (BN - 1);
    const int tid = threadIdx.x;

    if (g == 0 && tid == 0) {         // ws is 0xAA-poisoned before every call
        *loss_sum = 0.0f; *valid_cnt = 0u; *done = 0u;
    }

    for (int i = tid; i < 2 * NB; i += HT) hl[i] = 0;
    __syncthreads();

    const int pairs = PTOT / BN;      // 16384
    const int base  = sl * pairs;
    const float* x0 = x + (((long long)n * 2) << PLOG);
    const float* x1 = x0 + PTOT;
    const int*   tg = tgt + ((long long)n << PLOG);

#pragma unroll
    for (int it = 0; it < 4; ++it) {          // pairs/(HT*4) == 4
        const int p = base + it * HT * 4 + tid * 4;
        float4 a  = *(const float4*)(x0 + p);
        float4 b  = *(const float4*)(x1 + p);
        int4   t4 = *(const int4*)(tg + p);
        float xa[4] = {a.x, a.y, a.z, a.w};
        float xb[4] = {b.x, b.y, b.z, b.w};
        int   tt[4] = {t4.x, t4.y, t4.z, t4.w};
#pragma unroll
        for (int k = 0; k < 4; ++k) {
            const bool m0 = (tt[k] == 0);
            const bool m1 = (tt[k] == 1);
            float d0 = m0 ? 1.0f - xa[k] : xa[k];
            float d1 = m1 ? 1.0f - xb[k] : xb[k];
            int b0 = min((int)(d0 * (float)NB), NB - 1);
            int b1 = min((int)(d1 * (float)NB), NB - 1);
            atomicAdd(&hl[b0],      m0 ? 0x10000u : 1u);
            atomicAdd(&hl[NB + b1], m1 ? 0x10000u : 1u);
        }
    }
    __syncthreads();   // all LDS atomics visible before flush
    unsigned* outp = partial + (size_t)g * (2 * NB);
    for (int i = tid; i < 2 * NB; i += HT) outp[i] = hl[i];
}

// ------- Kernel 2: merge + scan + last-block final (64 x 1024) --------------
// Merge: thread (q,t) = (tid>>8, tid&255) accumulates buckets [4t,4t+4) over
// slices [4q,4q+4) with 4 uint4 loads, then combines across q via LDS
// atomics (4-way contention max). Scan: thread tid owns bucket b = NB-1-tid.
__global__ __launch_bounds__(ST, 8) void mergescan_k(
    const unsigned* __restrict__ partial, const float* __restrict__ cw,
    const float* __restrict__ tw, float* __restrict__ loss_sum,
    unsigned* __restrict__ valid_cnt, unsigned* __restrict__ done,
    float* __restrict__ out)
{
    const int seg = blockIdx.x;           // seg = (c<<5)|n
    const int c = seg >> 5, n = seg & 31;
    const int tid  = threadIdx.x;
    const int lane = tid & 63;
    const int wid  = tid >> 6;            // 16 waves

    __shared__ unsigned mh0[NB], mh1[NB];   // 8 KB merged counts

    mh0[tid] = 0; mh1[tid] = 0;             // ST == NB: one slot per thread
    __syncthreads();

    // ---- merge: 4 slices x uint4 (buckets 4t..4t+3) per thread ----
    {
        const int q = tid >> 8;             // slice group (4 slices each)
        const int t = tid & 255;            // bucket quad
        const unsigned* basep = partial +
            (((size_t)(n * BN + q * 4) * 2) + c) * NB + 4 * t;
        unsigned n0v[4] = {0, 0, 0, 0}, n1v[4] = {0, 0, 0, 0};
#pragma unroll
        for (int s = 0; s < 4; ++s) {
            uint4 v = *(const uint4*)(basep + (size_t)s * (2 * NB));
            n0v[0] += v.x & 0xFFFFu; n1v[0] += v.x >> 16;
            n0v[1] += v.y & 0xFFFFu; n1v[1] += v.y >> 16;
            n0v[2] += v.z & 0xFFFFu; n1v[2] += v.z >> 16;
            n0v[3] += v.w & 0xFFFFu; n1v[3] += v.w >> 16;
        }
#pragma unroll
        for (int j = 0; j < 4; ++j) {
            atomicAdd(&mh0[4 * t + j], n0v[j]);
            atomicAdd(&mh1[4 * t + j], n1v[j]);
        }
    }
    __syncthreads();

    // ---- scan phase: thread tid owns bucket b = NB-1-tid ----
    const int b = NB - 1 - tid;
    const unsigned n0 = mh0[b], n1 = mh1[b];
    const unsigned tot = n0 + n1;

    unsigned iA = tot, iS = n1;
#pragma unroll
    for (int off = 1; off < 64; off <<= 1) {
        unsigned tA = __shfl_up(iA, off, 64);
        unsigned tS = __shfl_up(iS, off, 64);
        if (lane >= off) { iA += tA; iS += tS; }
    }
    __shared__ unsigned wA[16], wS[16], wC[16];
    __shared__ int      wM[16];
    __shared__ float    wF[16];
    if (lane == 63) { wA[wid] = iA; wS[wid] = iS; }

    unsigned cgt = ((b >= B0_LO) ? n0 : 0u) + ((b < B1_HI) ? n1 : 0u);
    int mb = (n0 | n1) ? b : -1;
#pragma unroll
    for (int off = 1; off < 64; off <<= 1) {
        cgt += __shfl_xor(cgt, off, 64);
        mb = max(mb, __shfl_xor(mb, off, 64));
    }
    if (lane == 0) { wC[wid] = cgt; wM[wid] = mb; }
    __syncthreads();

    if (tid < 16) {                        // cross-wave scan in wave 0
        unsigned a = wA[tid], s2 = wS[tid];
#pragma unroll
        for (int off = 1; off < 16; off <<= 1) {
            unsigned tA = __shfl_up(a, off, 64);
            unsigned tS = __shfl_up(s2, off, 64);
            if (tid >= off) { a += tA; s2 += tS; }
        }
        wA[tid] = a; wS[tid] = s2;
    }
    __syncthreads();

    const unsigned gts   = wS[15];
    const unsigned exclA = iA - tot + (wid ? wA[wid - 1] : 0u);
    const unsigned exclS = iS - n1  + (wid ? wS[wid - 1] : 0u);

    float per_local = 0.0f;
    if (gts > 0 && (n0 | n1)) {
        float d_rep = ((float)b + 0.5f) * (1.0f / (float)NB);
        float U = (float)(gts + exclA - exclS);
        if (n1) per_local += (float)n1 * d_rep / U;
        unsigned s = exclS + n1;
        unsigned inter = gts - s;
        if (n0 && inter)
            per_local += d_rep * (float)inter * (float)n0 /
                         (U * (U + (float)n0));
    }
#pragma unroll
    for (int off = 1; off < 64; off <<= 1)
        per_local += __shfl_xor(per_local, off, 64);
    if (lane == 0) wF[wid] = per_local;
    __syncthreads();

    if (tid == 0) {
        float per = 0.0f;
        unsigned cntgt = 0;
        int max_b = -1;
        for (int i = 0; i < 16; ++i) {
            per += wF[i]; cntgt += wC[i]; max_b = max(max_b, wM[i]);
        }
        if (gts == 0)
            per = (max_b >= 0) ? ((float)max_b + 0.5f) * (1.0f / (float)NB) : 0.0f;
        const bool empty = (gts == 0) && (cntgt == 0);
        const float cwv = cw[c], twv = tw[n];
        const bool valid = (cwv != 0.0f) && !empty;
        if (valid) {
            atomicAdd(loss_sum, per * twv * cwv);   // device-scope, XCD-safe
            atomicAdd(valid_cnt, 1u);
        }
        __threadfence();
        unsigned old = atomicAdd(done, 1u);         // last block finalizes
        if (old == NSEG - 1) {
            float    L = atomicAdd(loss_sum, 0.0f); // coherent atomic readback
            unsigned V = atomicAdd(valid_cnt, 0u);
            out[0] = L / (float)NN / (float)V;
        }
    }
}

extern "C" void kernel_launch(void* const* d_in, const int* in_sizes, int n_in,
                              void* d_out, int out_size, void* d_ws, size_t ws_size,
                              hipStream_t stream)
{
    const float* x   = (const float*)d_in[0];   // [32,2,512,512] f32
    const int*   tgt = (const int*)d_in[1];     // [32,512,512] int
    const float* cw  = (const float*)d_in[2];   // [2]
    const float* tw  = (const float*)d_in[3];   // [32]
    float* out = (float*)d_out;

    // ws layout: [0,4) loss_sum f32, [4,8) valid_cnt u32, [8,12) done u32,
    // [512, 512 + NN*BN*2*NB*4 = 4 MiB) partial. (ws proven >= 32 MiB.)
    float*    loss_sum  = (float*)d_ws;
    unsigned* valid_cnt = (unsigned*)((char*)d_ws + 4);
    unsigned* done      = (unsigned*)((char*)d_ws + 8);
    unsigned* partial   = (unsigned*)((char*)d_ws + 512);

    hist_k     <<<NN * BN, HT, 0, stream>>>(x, tgt, partial, loss_sum,
                                            valid_cnt, done);
    mergescan_k<<<NSEG, ST, 0, stream>>>(partial, cw, tw, loss_sum,
                                         valid_cnt, done, out);
}